// Round 1
// baseline (303.721 us; speedup 1.0000x reference)
//
#include <hip/hip_runtime.h>
#include <hip/hip_bf16.h>
#include <math.h>

// Problem: single-head causal attention with fused QKV projection.
// B=16, T=4096, D_MODEL=512, HEAD_DIM=64. fp32 in/out, bf16 MFMA internally.

#define NB 16
#define NT 4096
#define DMODEL 512
#define HD 64

typedef unsigned short u16;
typedef __attribute__((ext_vector_type(8))) short bf16x8;
typedef __attribute__((ext_vector_type(4))) float f32x4;

__device__ __forceinline__ u16 f2bf(float x) {
  union { float f; unsigned u; } v; v.f = x;
  unsigned r = v.u + 0x7fffu + ((v.u >> 16) & 1u);  // RNE
  return (u16)(r >> 16);
}

// ---------------------------------------------------------------------------
// Kernel 1: Wt[n][k] = W_{n/64}[k][n%64] as bf16, n in [0,192), k in [0,512).
// Tiny (98K elems); gives contiguous-k B-fragments for the projection GEMM.
// ---------------------------------------------------------------------------
__global__ void prep_wt(const float* __restrict__ Wq, const float* __restrict__ Wk,
                        const float* __restrict__ Wv, u16* __restrict__ Wt) {
  int k0 = blockIdx.x * 16;
  int t = threadIdx.x;
#pragma unroll
  for (int i = 0; i < 12; ++i) {
    int idx = t + i * 256;      // [0, 3072)
    int n = idx % 192;
    int kk = idx / 192;         // [0, 16)
    const float* W = (n < 64) ? Wq : (n < 128) ? Wk : Wv;
    float w = W[(size_t)(k0 + kk) * 64 + (n & 63)];
    Wt[(size_t)n * 512 + k0 + kk] = f2bf(w);
  }
}

// ---------------------------------------------------------------------------
// Kernel 2: q|k|v = x @ [Wq|Wk|Wv], output bf16 [B*T][64] each.
// 512 threads (8 waves, 2x4 wave grid), BM=128, BN=192, BK=32.
// A staged fp32->bf16 through LDS; B fragments loaded straight from L2-hot Wt.
// ---------------------------------------------------------------------------
__global__ __launch_bounds__(512) void proj_qkv(const float* __restrict__ x,
                                                const u16* __restrict__ Wt,
                                                u16* __restrict__ qo,
                                                u16* __restrict__ ko,
                                                u16* __restrict__ vo) {
  __shared__ u16 As[128][48];   // 32 k + 16 pad, row stride 96 B (16B-aligned)
  int t = threadIdx.x;
  int m0 = blockIdx.x * 128;
  int lane = t & 63, wid = t >> 6;
  int wr = wid >> 2, wc = wid & 3;       // wave tile: rows wr*64, cols wc*48
  int g = lane >> 4, li = lane & 15;
  f32x4 acc[4][3];
#pragma unroll
  for (int i = 0; i < 4; ++i)
#pragma unroll
    for (int j = 0; j < 3; ++j) acc[i][j] = (f32x4){0.f, 0.f, 0.f, 0.f};

  int row = t >> 2, quad = t & 3;        // staging map: 128 rows x 4 quads of 8
  for (int k0 = 0; k0 < 512; k0 += 32) {
    __syncthreads();
    const float* src = x + (size_t)(m0 + row) * DMODEL + k0 + quad * 8;
    float4 f0 = *(const float4*)src;
    float4 f1 = *(const float4*)(src + 4);
    union { u16 s[8]; bf16x8 v; } tmp;
    tmp.s[0] = f2bf(f0.x); tmp.s[1] = f2bf(f0.y);
    tmp.s[2] = f2bf(f0.z); tmp.s[3] = f2bf(f0.w);
    tmp.s[4] = f2bf(f1.x); tmp.s[5] = f2bf(f1.y);
    tmp.s[6] = f2bf(f1.z); tmp.s[7] = f2bf(f1.w);
    *(bf16x8*)&As[row][quad * 8] = tmp.v;
    __syncthreads();

    bf16x8 a[4], bb[3];
#pragma unroll
    for (int mf = 0; mf < 4; ++mf)
      a[mf] = *(const bf16x8*)&As[wr * 64 + mf * 16 + li][g * 8];
#pragma unroll
    for (int nf = 0; nf < 3; ++nf)
      bb[nf] = *(const bf16x8*)(Wt + (size_t)(wc * 48 + nf * 16 + li) * 512 + k0 + g * 8);
#pragma unroll
    for (int mf = 0; mf < 4; ++mf)
#pragma unroll
      for (int nf = 0; nf < 3; ++nf)
        acc[mf][nf] = __builtin_amdgcn_mfma_f32_16x16x32_bf16(a[mf], bb[nf], acc[mf][nf], 0, 0, 0);
  }

  // D layout: col = lane&15, row = 4*(lane>>4)+r
#pragma unroll
  for (int nf = 0; nf < 3; ++nf) {
    int n = wc * 48 + nf * 16 + li;
    u16* dst = (n < 64) ? qo : (n < 128) ? ko : vo;
    int col = n & 63;
#pragma unroll
    for (int mf = 0; mf < 4; ++mf)
#pragma unroll
      for (int r = 0; r < 4; ++r) {
        int m = m0 + wr * 64 + mf * 16 + 4 * g + r;
        dst[(size_t)m * HD + col] = f2bf(acc[mf][nf][r]);
      }
  }
}

// ---------------------------------------------------------------------------
// Kernel 3: causal flash attention. Grid (T/64, B), 256 threads (4 waves).
// Wave w owns q rows [q0+w*16, q0+w*16+16). KV tiles of 64 staged in LDS.
// Softmax scale 1/8 folded into the exp2 constant (exact).
// ---------------------------------------------------------------------------
#define CEXP 0.18033688011112042f   // log2(e)/8

__global__ __launch_bounds__(256) void attn_fwd(const u16* __restrict__ qg,
                                                const u16* __restrict__ kg,
                                                const u16* __restrict__ vg,
                                                float* __restrict__ out) {
  __shared__ u16 Ks[64][72];        // K tile [key][d], pad 8 (row 144 B)
  __shared__ u16 Vt[64][72];        // V^T tile [d][key]
  __shared__ u16 Ps[4][16][72];     // per-wave P [q'][key]
  int t = threadIdx.x;
  int lane = t & 63, w = t >> 6;
  int g = lane >> 4, li = lane & 15;
  int qb = blockIdx.x, b = blockIdx.y;
  int q0 = qb * 64;
  const size_t base = (size_t)b * NT * HD;

  // Q fragments held in registers for the whole kernel (A-operand: row=li, k=8g+j)
  bf16x8 qf0 = *(const bf16x8*)(qg + base + (size_t)(q0 + w * 16 + li) * HD + g * 8);
  bf16x8 qf1 = *(const bf16x8*)(qg + base + (size_t)(q0 + w * 16 + li) * HD + 32 + g * 8);

  float m_run[4], l_run[4];
  f32x4 oacc[4];
#pragma unroll
  for (int r = 0; r < 4; ++r) { m_run[r] = -INFINITY; l_run[r] = 0.f; }
#pragma unroll
  for (int n = 0; n < 4; ++n) oacc[n] = (f32x4){0.f, 0.f, 0.f, 0.f};

  int srow = t >> 2, spart = t & 3;  // staging map: 64 rows x 4 parts of 16
  for (int it = 0; it <= qb; ++it) {
    int kv0 = it * 64;
    __syncthreads();   // previous tile's reads done before restage
    {
      const u16* ksrc = kg + base + (size_t)(kv0 + srow) * HD + spart * 16;
      bf16x8 a0 = *(const bf16x8*)ksrc;
      bf16x8 a1 = *(const bf16x8*)(ksrc + 8);
      *(bf16x8*)&Ks[srow][spart * 16] = a0;
      *(bf16x8*)&Ks[srow][spart * 16 + 8] = a1;
      const u16* vsrc = vg + base + (size_t)(kv0 + srow) * HD + spart * 16;
      bf16x8 b0 = *(const bf16x8*)vsrc;
      bf16x8 b1 = *(const bf16x8*)(vsrc + 8);
#pragma unroll
      for (int j = 0; j < 8; ++j) {   // transpose V into Vt (scalar writes)
        Vt[spart * 16 + j][srow] = (u16)b0[j];
        Vt[spart * 16 + 8 + j][srow] = (u16)b1[j];
      }
    }
    __syncthreads();

    // S = Q K^T : D layout => lane holds key col = li (+16s), q rows 4g+r
    f32x4 sv[4];
#pragma unroll
    for (int s = 0; s < 4; ++s) {
      bf16x8 kf0 = *(const bf16x8*)&Ks[s * 16 + li][g * 8];
      bf16x8 kf1 = *(const bf16x8*)&Ks[s * 16 + li][32 + g * 8];
      f32x4 c = (f32x4){0.f, 0.f, 0.f, 0.f};
      c = __builtin_amdgcn_mfma_f32_16x16x32_bf16(qf0, kf0, c, 0, 0, 0);
      c = __builtin_amdgcn_mfma_f32_16x16x32_bf16(qf1, kf1, c, 0, 0, 0);
      sv[s] = c;
    }
    if (it == qb) {  // diagonal tile: causal mask
#pragma unroll
      for (int s = 0; s < 4; ++s) {
        int key = kv0 + s * 16 + li;
#pragma unroll
        for (int r = 0; r < 4; ++r) {
          int qq = q0 + w * 16 + 4 * g + r;
          if (key > qq) sv[s][r] = -INFINITY;
        }
      }
    }

    // online softmax: row = across 16 lanes (keys) x 4 s-subtiles
    float mloc[4];
#pragma unroll
    for (int r = 0; r < 4; ++r)
      mloc[r] = fmaxf(fmaxf(sv[0][r], sv[1][r]), fmaxf(sv[2][r], sv[3][r]));
#pragma unroll
    for (int off = 1; off < 16; off <<= 1)
#pragma unroll
      for (int r = 0; r < 4; ++r)
        mloc[r] = fmaxf(mloc[r], __shfl_xor(mloc[r], off));
    float fr[4];
#pragma unroll
    for (int r = 0; r < 4; ++r) {
      float mn = fmaxf(m_run[r], mloc[r]);
      fr[r] = exp2f((m_run[r] - mn) * CEXP);
      m_run[r] = mn;
    }
    float psum[4] = {0.f, 0.f, 0.f, 0.f};
#pragma unroll
    for (int s = 0; s < 4; ++s)
#pragma unroll
      for (int r = 0; r < 4; ++r) {
        float p = exp2f((sv[s][r] - m_run[r]) * CEXP);
        psum[r] += p;
        Ps[w][4 * g + r][s * 16 + li] = f2bf(p);  // per-wave region, in-order DS
      }
#pragma unroll
    for (int off = 1; off < 16; off <<= 1)
#pragma unroll
      for (int r = 0; r < 4; ++r)
        psum[r] += __shfl_xor(psum[r], off);
#pragma unroll
    for (int r = 0; r < 4; ++r) l_run[r] = l_run[r] * fr[r] + psum[r];
#pragma unroll
    for (int n = 0; n < 4; ++n)
#pragma unroll
      for (int r = 0; r < 4; ++r) oacc[n][r] *= fr[r];

    // O += P V : A = P (row=li, k=key), B = V (col=d via Vt, k=key)
#pragma unroll
    for (int s2 = 0; s2 < 2; ++s2) {
      bf16x8 pf = *(const bf16x8*)&Ps[w][li][s2 * 32 + g * 8];
#pragma unroll
      for (int n = 0; n < 4; ++n) {
        bf16x8 vf = *(const bf16x8*)&Vt[n * 16 + li][s2 * 32 + g * 8];
        oacc[n] = __builtin_amdgcn_mfma_f32_16x16x32_bf16(pf, vf, oacc[n], 0, 0, 0);
      }
    }
  }

#pragma unroll
  for (int n = 0; n < 4; ++n)
#pragma unroll
    for (int r = 0; r < 4; ++r) {
      size_t o = base + (size_t)(q0 + w * 16 + 4 * g + r) * HD + n * 16 + li;
      out[o] = oacc[n][r] / l_run[r];
    }
}

// ---------------------------------------------------------------------------
extern "C" void kernel_launch(void* const* d_in, const int* in_sizes, int n_in,
                              void* d_out, int out_size, void* d_ws, size_t ws_size,
                              hipStream_t stream) {
  const float* x  = (const float*)d_in[0];
  const float* Wq = (const float*)d_in[1];
  const float* Wk = (const float*)d_in[2];
  const float* Wv = (const float*)d_in[3];
  float* out = (float*)d_out;

  // ws layout: Wt bf16 [192][512] | q | k | v bf16 [B*T][64]  (~24.2 MB total)
  u16* Wt  = (u16*)d_ws;
  u16* qws = (u16*)((char*)d_ws + 192 * 512 * 2);
  u16* kws = qws + (size_t)NB * NT * HD;
  u16* vws = kws + (size_t)NB * NT * HD;

  prep_wt<<<32, 256, 0, stream>>>(Wq, Wk, Wv, Wt);
  proj_qkv<<<(NB * NT) / 128, 512, 0, stream>>>(x, Wt, qws, kws, vws);
  attn_fwd<<<dim3(NT / 64, NB), 256, 0, stream>>>(qws, kws, vws, out);
}

// Round 2
// 276.649 us; speedup vs baseline: 1.0979x; 1.0979x over previous
//
#include <hip/hip_runtime.h>
#include <hip/hip_bf16.h>
#include <math.h>

// Single-head causal attention with fused QKV projection.
// B=16, T=4096, D_MODEL=512, HEAD_DIM=64. fp32 in/out, bf16 MFMA internally.
//
// R2 structure: attention is barrier-free. K and V^T fragments are read
// directly from global (L2/LLC-resident, 24 MB working set), V is emitted
// pre-transposed by the projection kernel, and causal work is balanced by
// pairing q-tile p with q-tile 255-p in the same wave (~65 tile-units each).

#define NB 16
#define NT 4096
#define DMODEL 512
#define HD 64
#define CEXP 0.18033688011112042f   // log2(e)/8  (softmax scale 1/sqrt(64) folded in)

typedef unsigned short u16;
typedef __attribute__((ext_vector_type(8))) short bf16x8;
typedef __attribute__((ext_vector_type(4))) float f32x4;

__device__ __forceinline__ u16 f2bf(float x) {
  union { float f; unsigned u; } v; v.f = x;
  unsigned r = v.u + 0x7fffu + ((v.u >> 16) & 1u);  // RNE
  return (u16)(r >> 16);
}

__device__ __forceinline__ u16 bfu(float x) {
  __hip_bfloat16 h = __float2bfloat16(x);
  return *(u16*)&h;
}

// ---------------------------------------------------------------------------
// Kernel 1: Wt[n][k] = W_{n/64}[k][n%64] as bf16, n in [0,192), k in [0,512).
// ---------------------------------------------------------------------------
__global__ void prep_wt(const float* __restrict__ Wq, const float* __restrict__ Wk,
                        const float* __restrict__ Wv, u16* __restrict__ Wt) {
  int k0 = blockIdx.x * 16;
  int t = threadIdx.x;
#pragma unroll
  for (int i = 0; i < 12; ++i) {
    int idx = t + i * 256;      // [0, 3072)
    int n = idx % 192;
    int kk = idx / 192;         // [0, 16)
    const float* W = (n < 64) ? Wq : (n < 128) ? Wk : Wv;
    float w = W[(size_t)(k0 + kk) * 64 + (n & 63)];
    Wt[(size_t)n * 512 + k0 + kk] = f2bf(w);
  }
}

// ---------------------------------------------------------------------------
// Kernel 2: q = x@Wq, k = x@Wk (row-major bf16 [B*T][64]);
//           vt = (x@Wv)^T per batch (bf16 [B][64][T]).
// 512 threads (8 waves, 2x4), BM=128, BN=192, BK=32.
// ---------------------------------------------------------------------------
__global__ __launch_bounds__(512) void proj_qkv(const float* __restrict__ x,
                                                const u16* __restrict__ Wt,
                                                u16* __restrict__ qo,
                                                u16* __restrict__ ko,
                                                u16* __restrict__ vt) {
  __shared__ u16 As[128][48];   // 32 k + 16 pad
  int t = threadIdx.x;
  int m0 = blockIdx.x * 128;
  int lane = t & 63, wid = t >> 6;
  int wr = wid >> 2, wc = wid & 3;
  int g = lane >> 4, li = lane & 15;
  f32x4 acc[4][3];
#pragma unroll
  for (int i = 0; i < 4; ++i)
#pragma unroll
    for (int j = 0; j < 3; ++j) acc[i][j] = (f32x4){0.f, 0.f, 0.f, 0.f};

  int row = t >> 2, quad = t & 3;
  for (int k0 = 0; k0 < 512; k0 += 32) {
    __syncthreads();
    const float* src = x + (size_t)(m0 + row) * DMODEL + k0 + quad * 8;
    float4 f0 = *(const float4*)src;
    float4 f1 = *(const float4*)(src + 4);
    union { u16 s[8]; bf16x8 v; } tmp;
    tmp.s[0] = f2bf(f0.x); tmp.s[1] = f2bf(f0.y);
    tmp.s[2] = f2bf(f0.z); tmp.s[3] = f2bf(f0.w);
    tmp.s[4] = f2bf(f1.x); tmp.s[5] = f2bf(f1.y);
    tmp.s[6] = f2bf(f1.z); tmp.s[7] = f2bf(f1.w);
    *(bf16x8*)&As[row][quad * 8] = tmp.v;
    __syncthreads();

    bf16x8 a[4], bb[3];
#pragma unroll
    for (int mf = 0; mf < 4; ++mf)
      a[mf] = *(const bf16x8*)&As[wr * 64 + mf * 16 + li][g * 8];
#pragma unroll
    for (int nf = 0; nf < 3; ++nf)
      bb[nf] = *(const bf16x8*)(Wt + (size_t)(wc * 48 + nf * 16 + li) * 512 + k0 + g * 8);
#pragma unroll
    for (int mf = 0; mf < 4; ++mf)
#pragma unroll
      for (int nf = 0; nf < 3; ++nf)
        acc[mf][nf] = __builtin_amdgcn_mfma_f32_16x16x32_bf16(a[mf], bb[nf], acc[mf][nf], 0, 0, 0);
  }

  // D layout: col = lane&15, row = 4*(lane>>4)+r
#pragma unroll
  for (int nf = 0; nf < 3; ++nf) {
    int n = wc * 48 + nf * 16 + li;
    if (n < 128) {
      u16* dst = (n < 64) ? qo : ko;
      int col = n & 63;
#pragma unroll
      for (int mf = 0; mf < 4; ++mf)
#pragma unroll
        for (int r = 0; r < 4; ++r) {
          int m = m0 + wr * 64 + mf * 16 + 4 * g + r;
          dst[(size_t)m * HD + col] = f2bf(acc[mf][nf][r]);
        }
    } else {
      int d = n - 128;
#pragma unroll
      for (int mf = 0; mf < 4; ++mf) {
        int mbase = m0 + wr * 64 + mf * 16 + 4 * g;   // 4-aligned, within one batch
        int bb2 = mbase >> 12, tt = mbase & 4095;
        ushort4 pk;
        pk.x = f2bf(acc[mf][nf][0]);
        pk.y = f2bf(acc[mf][nf][1]);
        pk.z = f2bf(acc[mf][nf][2]);
        pk.w = f2bf(acc[mf][nf][3]);
        *(ushort4*)(vt + ((size_t)bb2 * HD + d) * NT + tt) = pk;
      }
    }
  }
}

// ---------------------------------------------------------------------------
// Kernel 3: causal flash attention, barrier-free.
// Grid (32, B), 256 threads (4 waves). Wave w handles q-tiles p and 255-p
// (p = bx*4+w), 16 q-rows each, sequentially -> ~65 KV tiles per wave.
// K double-buffered in registers (prefetch next tile); V^T loaded per tile
// before softmax. P re-layout through wave-private LDS (no syncthreads).
// Row-sum accumulated via a ones-column MFMA.
// ---------------------------------------------------------------------------
__device__ __forceinline__ void run_qtile(
    int qt, int g, int li,
    const u16* __restrict__ qb, const u16* __restrict__ kb,
    const u16* __restrict__ vb, float* __restrict__ ob, u16* psw) {
  const int q0 = qt * 16;
  const int lim = qt >> 2;   // last KV tile index

  bf16x8 qf0 = *(const bf16x8*)(qb + (size_t)(q0 + li) * HD + g * 8);
  bf16x8 qf1 = *(const bf16x8*)(qb + (size_t)(q0 + li) * HD + 32 + g * 8);

  bf16x8 ones;
#pragma unroll
  for (int i = 0; i < 8; ++i) ones[i] = (short)0x3F80;

  float m_run[4];
  f32x4 lacc = (f32x4){0.f, 0.f, 0.f, 0.f};
  f32x4 oacc[4];
#pragma unroll
  for (int r = 0; r < 4; ++r) m_run[r] = -INFINITY;
#pragma unroll
  for (int n = 0; n < 4; ++n) oacc[n] = (f32x4){0.f, 0.f, 0.f, 0.f};

  u16* pw = psw + g * 288 + li;          // row (4g+r), col (s*16+li): +r*72+s*16
  const u16* pr = psw + li * 72 + g * 8; // row li, k chunk: +s2*32

  auto LOADK = [&](bf16x8 (&kf)[8], int jj) {
    const u16* kp = kb + (size_t)(jj * 64 + li) * HD + g * 8;
#pragma unroll
    for (int s = 0; s < 4; ++s) {
      kf[2 * s]     = *(const bf16x8*)(kp + s * 16 * HD);
      kf[2 * s + 1] = *(const bf16x8*)(kp + s * 16 * HD + 32);
    }
  };
  auto LOADV = [&](bf16x8 (&vf)[8], int jj) {
    const u16* vp = vb + (size_t)li * NT + jj * 64 + g * 8;
#pragma unroll
    for (int n = 0; n < 4; ++n) {
      vf[2 * n]     = *(const bf16x8*)(vp + (size_t)n * 16 * NT);
      vf[2 * n + 1] = *(const bf16x8*)(vp + (size_t)n * 16 * NT + 32);
    }
  };
  auto TILE = [&](bf16x8 (&kf)[8], bf16x8 (&vf)[8], int jj) {
    f32x4 sv[4];
#pragma unroll
    for (int s = 0; s < 4; ++s) {
      f32x4 c = (f32x4){0.f, 0.f, 0.f, 0.f};
      c = __builtin_amdgcn_mfma_f32_16x16x32_bf16(qf0, kf[2 * s], c, 0, 0, 0);
      c = __builtin_amdgcn_mfma_f32_16x16x32_bf16(qf1, kf[2 * s + 1], c, 0, 0, 0);
      sv[s] = c;
    }
    if (jj == lim) {   // causal mask on the diagonal tile
#pragma unroll
      for (int s = 0; s < 4; ++s) {
        int key = jj * 64 + s * 16 + li;
#pragma unroll
        for (int r = 0; r < 4; ++r)
          if (key > q0 + 4 * g + r) sv[s][r] = -INFINITY;
      }
    }
    // row max over 16 lanes (key axis)
    float mloc[4];
#pragma unroll
    for (int r = 0; r < 4; ++r)
      mloc[r] = fmaxf(fmaxf(sv[0][r], sv[1][r]), fmaxf(sv[2][r], sv[3][r]));
#pragma unroll
    for (int off = 1; off < 16; off <<= 1)
#pragma unroll
      for (int r = 0; r < 4; ++r)
        mloc[r] = fmaxf(mloc[r], __shfl_xor(mloc[r], off));
    float fr[4];
#pragma unroll
    for (int r = 0; r < 4; ++r) {
      float mn = fmaxf(m_run[r], mloc[r]);
      fr[r] = __builtin_amdgcn_exp2f((m_run[r] - mn) * CEXP);
      m_run[r] = mn;
    }
    // P = exp2((S - m) * CEXP), bf16, wave-private LDS re-layout
#pragma unroll
    for (int s = 0; s < 4; ++s)
#pragma unroll
      for (int r = 0; r < 4; ++r) {
        float p = __builtin_amdgcn_exp2f((sv[s][r] - m_run[r]) * CEXP);
        pw[r * 72 + s * 16] = bfu(p);
      }
    // rescale accumulators
#pragma unroll
    for (int n = 0; n < 4; ++n)
#pragma unroll
      for (int r = 0; r < 4; ++r) oacc[n][r] *= fr[r];
#pragma unroll
    for (int r = 0; r < 4; ++r) lacc[r] *= fr[r];
    // O += P V ; rowsum via ones column
#pragma unroll
    for (int s2 = 0; s2 < 2; ++s2) {
      bf16x8 pf = *(const bf16x8*)(pr + s2 * 32);
#pragma unroll
      for (int n = 0; n < 4; ++n)
        oacc[n] = __builtin_amdgcn_mfma_f32_16x16x32_bf16(pf, vf[2 * n + s2], oacc[n], 0, 0, 0);
      lacc = __builtin_amdgcn_mfma_f32_16x16x32_bf16(pf, ones, lacc, 0, 0, 0);
    }
  };

  bf16x8 kA[8], kB[8], vC[8];
  LOADK(kA, 0);
  int j = 0;
  while (true) {
    LOADV(vC, j);
    if (j < lim) LOADK(kB, j + 1);
    TILE(kA, vC, j);
    if (++j > lim) break;
    LOADV(vC, j);
    if (j < lim) LOADK(kA, j + 1);
    TILE(kB, vC, j);
    if (++j > lim) break;
  }

  float inv[4];
#pragma unroll
  for (int r = 0; r < 4; ++r) inv[r] = 1.0f / lacc[r];
#pragma unroll
  for (int n = 0; n < 4; ++n)
#pragma unroll
    for (int r = 0; r < 4; ++r)
      ob[(size_t)(q0 + 4 * g + r) * HD + n * 16 + li] = oacc[n][r] * inv[r];
}

__global__ __launch_bounds__(256, 2) void attn_fwd2(const u16* __restrict__ qg,
                                                    const u16* __restrict__ kg,
                                                    const u16* __restrict__ vtg,
                                                    float* __restrict__ out) {
  __shared__ u16 Ps[4][16][72];
  int t = threadIdx.x;
  int lane = t & 63, w = t >> 6;
  int g = lane >> 4, li = lane & 15;
  int b = blockIdx.y;
  int p = blockIdx.x * 4 + w;          // [0,128)

  const u16* qb = qg + (size_t)b * NT * HD;
  const u16* kb = kg + (size_t)b * NT * HD;
  const u16* vb = vtg + (size_t)b * HD * NT;
  float* ob = out + (size_t)b * NT * HD;
  u16* psw = &Ps[w][0][0];

  run_qtile(p, g, li, qb, kb, vb, ob, psw);        // short member
  run_qtile(255 - p, g, li, qb, kb, vb, ob, psw);  // long member
}

// ---------------------------------------------------------------------------
extern "C" void kernel_launch(void* const* d_in, const int* in_sizes, int n_in,
                              void* d_out, int out_size, void* d_ws, size_t ws_size,
                              hipStream_t stream) {
  const float* x  = (const float*)d_in[0];
  const float* Wq = (const float*)d_in[1];
  const float* Wk = (const float*)d_in[2];
  const float* Wv = (const float*)d_in[3];
  float* out = (float*)d_out;

  // ws layout: Wt bf16 [192][512] | q [B*T][64] | k [B*T][64] | vt [B][64][T]
  u16* Wt  = (u16*)d_ws;
  u16* qws = (u16*)((char*)d_ws + 192 * 512 * 2);
  u16* kws = qws + (size_t)NB * NT * HD;
  u16* vtw = kws + (size_t)NB * NT * HD;

  prep_wt<<<32, 256, 0, stream>>>(Wq, Wk, Wv, Wt);
  proj_qkv<<<(NB * NT) / 128, 512, 0, stream>>>(x, Wt, qws, kws, vtw);
  attn_fwd2<<<dim3(32, NB), 256, 0, stream>>>(qws, kws, vtw, out);
}